// Round 16
// baseline (5742.437 us; speedup 1.0000x reference)
//
#include <hip/hip_runtime.h>
#include <hip/hip_bf16.h>
#include <math.h>

#define B_ 8
#define S_ 4096
#define D_ 768
#define NH_ 4
#define DH_ 192
#define NTOT_ 768   // 4*DH_

typedef __attribute__((ext_vector_type(8))) short short8;
typedef __attribute__((ext_vector_type(4))) float floatx4;
typedef __attribute__((ext_vector_type(4))) short short4v;
typedef _Float16 f16;
typedef __attribute__((ext_vector_type(8))) _Float16 h8;

__device__ __forceinline__ short f2bs(float f) {
  union { float f; unsigned u; } v; v.f = f;
  unsigned r = v.u + 0x7FFFu + ((v.u >> 16) & 1u);
  return (short)(r >> 16);
}
__device__ __forceinline__ float bs2f(unsigned short s) {
  union { unsigned u; float f; } v; v.u = ((unsigned)s) << 16;
  return v.f;
}

// f16 MFMA, B in AGPR (native read, no shuttle), acc in VGPR.
// _FIRST variant: s_nop 3 covers the VALU(zero-init)->MFMA SrcC hazard the
// compiler cannot see inside inline asm (R13/R15's deterministic 0.21875 —
// identical across dtypes and guard placement -> pre-MFMA hazard).
__device__ __forceinline__ void MFMA_AB1(floatx4& acc, h8 a, h8 b) {
  asm("s_nop 3\n\tv_mfma_f32_16x16x32_f16 %0, %1, %2, %0"
      : "+v"(acc) : "v"(a), "a"(b));
}
__device__ __forceinline__ void MFMA_AB(floatx4& acc, h8 a, h8 b) {
  asm("v_mfma_f32_16x16x32_f16 %0, %1, %2, %0" : "+v"(acc) : "v"(a), "a"(b));
}
// Post-MFMA guard: D-write -> VALU/DS-read wait states (32 cy, margin).
__device__ __forceinline__ void MFMA_GUARD(floatx4& a0, floatx4& a1,
                                           floatx4& a2, floatx4& a3) {
  asm volatile("s_nop 7\n\ts_nop 7\n\ts_nop 7\n\ts_nop 7"
               : "+v"(a0), "+v"(a1), "+v"(a2), "+v"(a3));
}

// ---------------- K0: weights -> bf16, fragment-friendly [hg][o][d] ----------------
__global__ __launch_bounds__(256) void wconv_kernel(
    const float* __restrict__ wf, const float* __restrict__ wi,
    const float* __restrict__ wz, const float* __restrict__ wo,
    short* __restrict__ Wbf)
{
  int idx = blockIdx.x * 256 + threadIdx.x;      // < 16*36864
  int hg = idx / (DH_ * DH_);
  int r  = idx % (DH_ * DH_);
  int h = hg >> 2, g = hg & 3;
  const float* W = (g == 0) ? wf : (g == 1) ? wi : (g == 2) ? wz : wo;
  Wbf[idx] = f2bs(W[(size_t)h * DH_ * DH_ + r]);
}

// ---------------- K1: depthwise causal conv + SiLU; also bf16 copy of x ----------------
__global__ __launch_bounds__(256) void conv_silu_kernel(
    const float* __restrict__ x, const float* __restrict__ cw, const float* __restrict__ cb,
    short* __restrict__ xb, short* __restrict__ xcb)
{
  const int b  = blockIdx.x / (S_ / 64);
  const int s0 = (blockIdx.x % (S_ / 64)) * 64;
  const int tid = threadIdx.x;
  float wv[3][4], bias[3], win[3][3];
  for (int j = 0; j < 3; ++j) {
    int d = tid + j * 256;
    for (int k = 0; k < 4; ++k) wv[j][k] = cw[d * 4 + k];
    bias[j] = cb[d];
    for (int p = 0; p < 3; ++p) {
      int s = s0 - 3 + p;
      win[j][p] = (s >= 0) ? x[((size_t)b * S_ + s) * D_ + d] : 0.f;
    }
  }
  for (int i = 0; i < 64; ++i) {
    size_t base = ((size_t)b * S_ + (s0 + i)) * D_;
    for (int j = 0; j < 3; ++j) {
      int d = tid + j * 256;
      float xc = x[base + d];
      float a = bias[j] + win[j][0] * wv[j][0] + win[j][1] * wv[j][1]
                        + win[j][2] * wv[j][2] + xc * wv[j][3];
      float sv = a / (1.f + __expf(-a));
      xb[base + d]  = f2bs(xc);
      xcb[base + d] = f2bs(sv);
      win[j][0] = win[j][1]; win[j][1] = win[j][2]; win[j][2] = xc;
    }
  }
}

// ---------------- K2: headwise projections (+r_bias folded) -> P[h][b][s][e*4+g] ----
__global__ __launch_bounds__(256) void proj_kernel(
    const short* __restrict__ xb, const short* __restrict__ xcb,
    const short* __restrict__ Wbf, const float* __restrict__ rb,
    short* __restrict__ P)
{
  const int hg = blockIdx.y;
  const int h = hg >> 2, g = hg & 3;
  const short* A  = (g < 2) ? xcb : xb;           // gi,gf from conv(x); gz,go from x
  const short* Wb = Wbf + (size_t)hg * (DH_ * DH_);
  const int tid = threadIdx.x, w = tid >> 6, l = tid & 63;
  const int l15 = l & 15, lg = l >> 4;
  const int R0 = blockIdx.x * 256 + w * 64;

  float rbv[12];
#pragma unroll
  for (int nt = 0; nt < 12; ++nt)
    rbv[nt] = rb[(g * NH_ + h) * DH_ + l15 + nt * 16];

  for (int mp = 0; mp < 2; ++mp) {
    const int rb0 = R0 + mp * 32;
    floatx4 acc[2][12];
    for (int u = 0; u < 2; ++u)
      for (int nt = 0; nt < 12; ++nt) acc[u][nt] = (floatx4){0.f, 0.f, 0.f, 0.f};
    const short* Ar = A + (size_t)(rb0 + l15) * D_ + h * DH_ + lg * 8;
    const short* Bp = Wb + l15 * DH_ + lg * 8;
    for (int kk = 0; kk < 6; ++kk) {
      short8 a0 = *(const short8*)(Ar + kk * 32);
      short8 a1 = *(const short8*)(Ar + (size_t)16 * D_ + kk * 32);
      for (int nt = 0; nt < 12; ++nt) {
        short8 bf = *(const short8*)(Bp + nt * 16 * DH_ + kk * 32);
        acc[0][nt] = __builtin_amdgcn_mfma_f32_16x16x32_bf16(a0, bf, acc[0][nt], 0, 0, 0);
        acc[1][nt] = __builtin_amdgcn_mfma_f32_16x16x32_bf16(a1, bf, acc[1][nt], 0, 0, 0);
      }
    }
    for (int u = 0; u < 2; ++u) {
      for (int q = 0; q < 4; ++q) {
        int row = rb0 + u * 16 + lg * 4 + q;
        int s = row & (S_ - 1);
        int bb = row >> 12;
        // packed gate-interleaved layout: column e*4 + g, e = l15 + nt*16
        size_t ob = (((size_t)h * B_ + bb) * S_ + s) * NTOT_ + l15 * 4 + g;
        for (int nt = 0; nt < 12; ++nt)
          P[ob + nt * 64] = f2bs(acc[u][nt][q] + rbv[nt]);
      }
    }
  }
}

// ---------------- K3: sLSTM scan, 8 chains batched in MFMA M dimension (f16) ----------
// ONE WG (768 thr, 12 waves) per head h; chains b=0..7 ride in MFMA A-rows 0-7.
// 288 MFMA/CU/step amortized over 8 chains (matrix-pipe floor ~1400 cy).
// asm MFMA with B in AGPR ("a") -> no accvgpr shuttle (R14's ~1150 cy/step).
// Hazard discipline: s_nop before FIRST MFMA of each acc chain (VALU zero-init
// -> SrcC read), none between same-acc MFMAs (pipe forwards), 32-cy guard
// before VALU/DS reads of D. Structure otherwise identical to PASSING R14.
__global__ __launch_bounds__(768)
void scan_kernel(short* P_, const float* __restrict__ rk)
{
  const int h  = blockIdx.x;       // 0..3
  const int t0 = threadIdx.x;
  const int w  = t0 >> 6, l = t0 & 63;
  const int l15 = l & 15, lg = l >> 4;

  __shared__ __align__(16) f16 y_lds[2][16][200];        // f16, rows 8-15 = 0
  __shared__ __align__(16) float raw_lds[12][8][16][4];  // [wave][chain][e4][gate]

  const float* Rh = rk + (size_t)h * (DH_ * NTOT_);   // [k][g*192+e]

  // B-fragments (f16): wave w, gate g -> n-window g*192 + 16w .. +16
  // Only consumed via "a" -> allocator places them in AGPRs (native MFMA read).
  h8 Bf[4][6];
#pragma unroll
  for (int g = 0; g < 4; ++g) {
#pragma unroll
    for (int kk = 0; kk < 6; ++kk) {
      h8 v;
#pragma unroll
      for (int j = 0; j < 8; ++j) {
        const int k = kk * 32 + lg * 8 + j;
        v[j] = (f16)Rh[(size_t)k * NTOT_ + g * DH_ + w * 16 + l15];
      }
      Bf[g][kk] = v;
    }
  }

  for (int idx = t0; idx < 2 * 16 * 200; idx += 768)
    ((f16*)y_lds)[idx] = (f16)0.f;

  const int e  = w * 16 + l15;         // this thread's element
  const int c0 = lg, c1 = lg + 4;      // its two chains
  short* Pb0 = P_ + ((size_t)(h * B_ + c0) * S_) * NTOT_;
  short* Pb1 = P_ + ((size_t)(h * B_ + c1) * S_) * NTOT_;

  float cc0 = 0.f, nn0 = 0.f, mm0 = 0.f;
  float cc1 = 0.f, nn1 = 0.f, mm1 = 0.f;
  short4v wxc0 = *(const short4v*)(Pb0 + e * 4);
  short4v wxc1 = *(const short4v*)(Pb1 + e * 4);
  __syncthreads();

#pragma unroll 1
  for (int t = 0; t < S_; ++t) {
    short4v wxn0 = {}, wxn1 = {};
    if (t + 1 < S_) {
      wxn0 = *(const short4v*)(Pb0 + (size_t)(t + 1) * NTOT_ + e * 4);
      wxn1 = *(const short4v*)(Pb1 + (size_t)(t + 1) * NTOT_ + e * 4);
    }
    const int cur = t & 1, nxt = cur ^ 1;

    // ---- matvec: 24 asm f16 MFMA/wave, A = y rows (chains), B = AGPR frags ----
    floatx4 a0 = (floatx4){0.f,0.f,0.f,0.f};
    floatx4 a1 = (floatx4){0.f,0.f,0.f,0.f};
    floatx4 a2 = (floatx4){0.f,0.f,0.f,0.f};
    floatx4 a3 = (floatx4){0.f,0.f,0.f,0.f};
    {
      h8 A = *(const h8*)&y_lds[cur][l15][lg * 8];
      MFMA_AB1(a0, A, Bf[0][0]);
      MFMA_AB1(a1, A, Bf[1][0]);
      MFMA_AB1(a2, A, Bf[2][0]);
      MFMA_AB1(a3, A, Bf[3][0]);
    }
#pragma unroll
    for (int kk = 1; kk < 6; ++kk) {
      h8 A = *(const h8*)&y_lds[cur][l15][kk * 32 + lg * 8];
      MFMA_AB(a0, A, Bf[0][kk]);
      MFMA_AB(a1, A, Bf[1][kk]);
      MFMA_AB(a2, A, Bf[2][kk]);
      MFMA_AB(a3, A, Bf[3][kk]);
    }
    MFMA_GUARD(a0, a1, a2, a3);   // D-write -> VALU/DS-read wait states

    // ---- intra-wave raw exchange: D row (lg*4+j) = chain, col l15 = e4 ----
    if (l < 32) {
#pragma unroll
      for (int j = 0; j < 4; ++j) {
        floatx4 v = (floatx4){a0[j], a1[j], a2[j], a3[j]};
        *(floatx4*)&raw_lds[w][lg * 4 + j][l15][0] = v;
      }
    }
    floatx4 r0 = *(const floatx4*)&raw_lds[w][c0][l15][0];
    floatx4 r1 = *(const floatx4*)&raw_lds[w][c1][l15][0];

    // ---- gate math: chain c0 ----
    f16 yh0, yh1;
    {
      float ir  = bs2f((unsigned short)wxc0[0]) + r0[0];
      float fr  = bs2f((unsigned short)wxc0[1]) + r0[1];
      float zr  = bs2f((unsigned short)wxc0[2]) + r0[2];
      float orr = bs2f((unsigned short)wxc0[3]) + r0[3];
      float lsf = fminf(fr, 0.f) - __logf(1.f + __expf(-fabsf(fr)));
      float lfm = mm0 + lsf;
      float mnew = fmaxf(ir, lfm);
      float ig = __expf(ir - mnew);
      float fg = __expf(lfm - mnew);
      float e2z = __expf(2.f * zr);
      float tz = 1.f - 2.f * __builtin_amdgcn_rcpf(e2z + 1.f);
      cc0 = fg * cc0 + ig * tz;
      nn0 = fg * nn0 + ig;
      mm0 = mnew;
      float sg = __builtin_amdgcn_rcpf(1.f + __expf(-orr));
      yh0 = (f16)(sg * cc0 * __builtin_amdgcn_rcpf(nn0));
    }
    // ---- chain c1 ----
    {
      float ir  = bs2f((unsigned short)wxc1[0]) + r1[0];
      float fr  = bs2f((unsigned short)wxc1[1]) + r1[1];
      float zr  = bs2f((unsigned short)wxc1[2]) + r1[2];
      float orr = bs2f((unsigned short)wxc1[3]) + r1[3];
      float lsf = fminf(fr, 0.f) - __logf(1.f + __expf(-fabsf(fr)));
      float lfm = mm1 + lsf;
      float mnew = fmaxf(ir, lfm);
      float ig = __expf(ir - mnew);
      float fg = __expf(lfm - mnew);
      float e2z = __expf(2.f * zr);
      float tz = 1.f - 2.f * __builtin_amdgcn_rcpf(e2z + 1.f);
      cc1 = fg * cc1 + ig * tz;
      nn1 = fg * nn1 + ig;
      mm1 = mnew;
      float sg = __builtin_amdgcn_rcpf(1.f + __expf(-orr));
      yh1 = (f16)(sg * cc1 * __builtin_amdgcn_rcpf(nn1));
    }

    // y broadcast (f16 A for next step) + f16 history for gnorm
    y_lds[nxt][c0][e] = yh0;
    y_lds[nxt][c1][e] = yh1;
    {
      union { f16 hh; short ss; } u0, u1;
      u0.hh = yh0; u1.hh = yh1;
      Pb0[(size_t)t * NTOT_ + e] = u0.ss;
      Pb1[(size_t)t * NTOT_ + e] = u1.ss;
    }
    wxc0 = wxn0; wxc1 = wxn1;
    __syncthreads();
  }
}

// ---------------- K4: groupnorm over DH per (h,b,s) row ----------------
__global__ __launch_bounds__(256) void gnorm_kernel(
    const short* __restrict__ yws, const float* __restrict__ gnw,
    float* __restrict__ out)
{
  const int row = blockIdx.x * 4 + (threadIdx.x >> 6);   // (h,b,s), 0..131071
  const int l = threadIdx.x & 63;
  const int h = row >> 15;
  const int b = (row >> 12) & 7;
  const int s = row & (S_ - 1);
  const short* yr = yws + (size_t)row * NTOT_;
  float v[3];
  float su = 0.f, sq = 0.f;
#pragma unroll
  for (int j = 0; j < 3; ++j) {
    unsigned short u = (unsigned short)yr[l + j * 64];
    union { unsigned short u; f16 h; } cv; cv.u = u;
    v[j] = (float)cv.h;
    su += v[j]; sq += v[j] * v[j];
  }
  for (int off = 32; off; off >>= 1) {
    su += __shfl_xor(su, off);
    sq += __shfl_xor(sq, off);
  }
  float mean = su * (1.f / DH_);
  float var = sq * (1.f / DH_) - mean * mean;
  float rs = rsqrtf(var + 1e-5f);
  float* orow = out + ((size_t)b * S_ + s) * D_ + h * DH_;
#pragma unroll
  for (int j = 0; j < 3; ++j)
    orow[l + j * 64] = (v[j] - mean) * rs * gnw[h * DH_ + l + j * 64];
}

extern "C" void kernel_launch(void* const* d_in, const int* in_sizes, int n_in,
                              void* d_out, int out_size, void* d_ws, size_t ws_size,
                              hipStream_t stream) {
  const float* x   = (const float*)d_in[0];
  const float* cw  = (const float*)d_in[1];
  const float* cb  = (const float*)d_in[2];
  const float* wf  = (const float*)d_in[3];
  const float* wi  = (const float*)d_in[4];
  const float* wz  = (const float*)d_in[5];
  const float* wo  = (const float*)d_in[6];
  const float* rk  = (const float*)d_in[7];
  const float* rb  = (const float*)d_in[8];
  const float* gnw = (const float*)d_in[9];
  float* out = (float*)d_out;

  // Workspace: P (bf16 Wx, [h][b][s][768]) = 201,326,592 B; Wbf = 1,179,648 B
  short* P   = (short*)d_ws;
  short* Wbf = (short*)((char*)d_ws + (size_t)201326592);
  // Reuse d_out (100,663,296 B) as scratch for bf16 x / conv(x); gnorm overwrites it.
  short* xb  = (short*)d_out;
  short* xcb = (short*)((char*)d_out + (size_t)50331648);

  wconv_kernel<<<dim3(2304), 256, 0, stream>>>(wf, wi, wz, wo, Wbf);
  conv_silu_kernel<<<dim3(512), 256, 0, stream>>>(x, cw, cb, xb, xcb);
  proj_kernel<<<dim3(128, 16), 256, 0, stream>>>(xb, xcb, Wbf, rb, P);
  scan_kernel<<<dim3(4), 768, 0, stream>>>(P, rk);
  gnorm_kernel<<<dim3(32768), 256, 0, stream>>>(P, gnw, out);
}